// Round 1
// 149.164 us; speedup vs baseline: 1.0231x; 1.0231x over previous
//
#include <hip/hip_runtime.h>

// KruskalLinearLayer — FUSED single kernel.
//   y[n,abc] = sum_r g0[a,r]g1[b,r]g2[c,r] * s[n,r] + bias[abc]
//   s[n,r]   = sum_{d,e,f} g3[d,r]g4[e,r]g5[f,r] * x[n,def]
//   g_m = f_m @ c_m  (16x8 @ 8x16)
//
// R1-R5 lesson (kept): no per-row 64-VGPR array. The only big register
// arrays are LOOP-INVARIANT per-wave weights w1[16] / wb[16] (f32x4 each,
// 128 VGPR total), loaded once from LDS. Per-row live set is s[16] + xd.
// R6 was a 2-kernel split through d_ws; this round fuses the phases:
//  - one dispatch instead of two (removes launch + serialization latency)
//  - no S round trip
//  - the x read stream and out write stream interleave in one wave,
//    so HBM sees mixed rd/wr instead of two serialized pure streams.
// Every lane computes the full butterfly-allreduced s[0..15] (it needs
// all 16 for every output chunk anyway), then emits all 16 chunks of
// the SAME row: chunk-dependent g0 column + bias come from LDS as
// uniform/contiguous b128 reads, never registers.

typedef float f32x4 __attribute__((ext_vector_type(4)));

#define WPB 4   // waves per block

__global__ __launch_bounds__(256, 2)
void kruskal_fused(const float* __restrict__ x,
                   const float* __restrict__ c0, const float* __restrict__ c1,
                   const float* __restrict__ c2, const float* __restrict__ c3,
                   const float* __restrict__ c4, const float* __restrict__ c5,
                   const float* __restrict__ f0, const float* __restrict__ f1,
                   const float* __restrict__ f2, const float* __restrict__ f3,
                   const float* __restrict__ f4, const float* __restrict__ f5,
                   const float* __restrict__ bias,
                   float* __restrict__ out, int N)
{
    __shared__ __align__(16) float g3t[256];  // [d][r]  (uniform f32x4 reads per d)
    __shared__ __align__(16) float g4t[256];  // [r][e]
    __shared__ __align__(16) float g5t[256];  // [r][f]
    __shared__ __align__(16) float g0c[256];  // [a][r]  (uniform f32x4 column reads per chunk)
    __shared__ __align__(16) float g1t[256];  // [r][b]
    __shared__ __align__(16) float g2t[256];  // [r][c]
    __shared__ __align__(16) float bsh[4096]; // staged bias (16 KB)

    const int tid = threadIdx.x;
    {
        const int i = tid >> 4, r = tid & 15;
        float a0 = 0.f, a1 = 0.f, a2 = 0.f, a3 = 0.f, a4 = 0.f, a5 = 0.f;
#pragma unroll
        for (int k = 0; k < 8; ++k) {
            a0 += f0[i * 8 + k] * c0[k * 16 + r];
            a1 += f1[i * 8 + k] * c1[k * 16 + r];
            a2 += f2[i * 8 + k] * c2[k * 16 + r];
            a3 += f3[i * 8 + k] * c3[k * 16 + r];
            a4 += f4[i * 8 + k] * c4[k * 16 + r];
            a5 += f5[i * 8 + k] * c5[k * 16 + r];
        }
        g0c[i * 16 + r] = a0;   // [a][r]
        g1t[r * 16 + i] = a1;   // [r][b]
        g2t[r * 16 + i] = a2;   // [r][c]
        g3t[i * 16 + r] = a3;   // [d][r]
        g4t[r * 16 + i] = a4;   // [r][e]
        g5t[r * 16 + i] = a5;   // [r][f]
    }
    {   // stage bias: 1024 f32x4, 256 threads x 4, coalesced
        const f32x4* b4 = (const f32x4*)bias;
        f32x4* bs4 = (f32x4*)bsh;
#pragma unroll
        for (int j = 0; j < 4; ++j) bs4[j * 256 + tid] = b4[j * 256 + tid];
    }
    __syncthreads();

    const int lane = tid & 63, waveId = tid >> 6;
    const int eb  = lane >> 2;         // e (phase1) / b (phase2)
    const int fcb = (lane & 3) * 4;    // f base     / c base

    // loop-invariant lane weights — the ONLY big register arrays (128 VGPR)
    f32x4 w1[16], wb[16];
#pragma unroll
    for (int r = 0; r < 16; ++r) {
        w1[r] = (*(const f32x4*)&g5t[r * 16 + fcb]) * g4t[r * 16 + eb];
        wb[r] = (*(const f32x4*)&g2t[r * 16 + fcb]) * g1t[r * 16 + eb];
    }

    const int wgl   = blockIdx.x * WPB + waveId;
    const int total = gridDim.x * WPB;
    for (int n = wgl; n < N; n += total) {
        const float* xn = x + (size_t)n * 4096;

        // ---- phase 1: s[r] = sum_def g3 g4 g5 x ----
        float s[16];
#pragma unroll
        for (int r = 0; r < 16; ++r) s[r] = 0.f;

        // unroll 2 ONLY: forbid hoisting all 16 loads (the R2/R4 spill trigger)
#pragma unroll 2
        for (int d = 0; d < 16; ++d) {
            const f32x4 xd = __builtin_nontemporal_load(
                (const f32x4*)(xn + d * 256 + lane * 4));
#pragma unroll
            for (int rq = 0; rq < 4; ++rq) {
                const f32x4 g3q = *(const f32x4*)&g3t[d * 16 + rq * 4]; // uniform
#pragma unroll
                for (int rr = 0; rr < 4; ++rr) {
                    const int r = rq * 4 + rr;
                    const float p = w1[r].x * xd.x + w1[r].y * xd.y
                                  + w1[r].z * xd.z + w1[r].w * xd.w;
                    s[r] += g3q[rr] * p;
                }
            }
        }

        // wave-wide allreduce of each s[r] (every lane needs all 16)
#pragma unroll
        for (int r = 0; r < 16; ++r) {
            float v = s[r];
            v += __shfl_xor(v, 1, 64);
            v += __shfl_xor(v, 2, 64);
            v += __shfl_xor(v, 4, 64);
            v += __shfl_xor(v, 8, 64);
            v += __shfl_xor(v, 16, 64);
            v += __shfl_xor(v, 32, 64);
            s[r] = v;
        }

        // ---- phase 2: all 16 output chunks of this row ----
        float* on = out + (size_t)n * 4096;
#pragma unroll 2
        for (int a = 0; a < 16; ++a) {
            f32x4 acc = *(const f32x4*)&bsh[a * 256 + lane * 4];
#pragma unroll
            for (int rq = 0; rq < 4; ++rq) {
                const f32x4 g0q = *(const f32x4*)&g0c[a * 16 + rq * 4]; // uniform
#pragma unroll
                for (int rr = 0; rr < 4; ++rr) {
                    const int r = rq * 4 + rr;
                    acc += (s[r] * g0q[rr]) * wb[r];
                }
            }
            __builtin_nontemporal_store(
                acc, (f32x4*)(on + a * 256 + lane * 4));
        }
    }
}

extern "C" void kernel_launch(void* const* d_in, const int* in_sizes, int n_in,
                              void* d_out, int out_size, void* d_ws, size_t ws_size,
                              hipStream_t stream) {
    const float* x  = (const float*)d_in[0];
    const float* c0 = (const float*)d_in[1];
    const float* c1 = (const float*)d_in[2];
    const float* c2 = (const float*)d_in[3];
    const float* c3 = (const float*)d_in[4];
    const float* c4 = (const float*)d_in[5];
    const float* c5 = (const float*)d_in[6];
    const float* f0 = (const float*)d_in[7];
    const float* f1 = (const float*)d_in[8];
    const float* f2 = (const float*)d_in[9];
    const float* f3 = (const float*)d_in[10];
    const float* f4 = (const float*)d_in[11];
    const float* f5 = (const float*)d_in[12];
    const float* bias = (const float*)d_in[13];
    float* out = (float*)d_out;
    (void)d_ws; (void)ws_size;

    const int N = in_sizes[0] / 4096;

    kruskal_fused<<<dim3(1024), dim3(256), 0, stream>>>(
        x, c0, c1, c2, c3, c4, c5, f0, f1, f2, f3, f4, f5, bias, out, N);
}